// Round 11
// baseline (413.239 us; speedup 1.0000x reference)
//
#include <hip/hip_runtime.h>
#include <hip/hip_cooperative_groups.h>
#include <math.h>

namespace cg = cooperative_groups;

#define ALPHA 0.2f
#define BETA 1.0f
#define EPSV 1e-8f
#define LOG2E 1.4426950408889634f
#define LN2 0.6931471805599453f

#define BATCH 4096
#define RR 18
#define KT 17            // R-1 targets per row
#define DD 256
#define NTGT (BATCH*KT)  // 69632 total targets

#define BMW 32           // anchors per wave (R8 partition)
#define BMB 128          // anchors per block
#define MBLK (BATCH/BMB) // 32
#define BN 64            // targets per LDS chunk
#define NCHUNKT (NTGT/BN)    // 1088 total chunks
#define NSPLIT 136           // N splits
#define NCHUNK (NCHUNKT/NSPLIT) // 8 chunks per task
#define NTASK (MBLK*NSPLIT)  // 4352 gemm tasks
#define NSLOT (NSPLIT*2)     // 272 per-anchor partial slots
#define CHUNK_BYTES (BN*DD)  // 16384 fp8, fragment-ordered
#define GRID 512             // 2 blocks/CU — safely under coop co-residency cap

typedef int   i32x8  __attribute__((ext_vector_type(8)));
typedef float f32x16 __attribute__((ext_vector_type(16)));

__device__ inline void gl_lds16(const void* g, void* l){
  __builtin_amdgcn_global_load_lds(
      (const __attribute__((address_space(1))) unsigned int*)g,
      (__attribute__((address_space(3))) unsigned int*)l, 16, 0, 0);
}

__device__ inline int pk8(float a, float b, float c, float d){
  int p = __builtin_amdgcn_cvt_pk_fp8_f32(a, b, 0, false);
  return  __builtin_amdgcn_cvt_pk_fp8_f32(c, d, p, true);
}

__device__ inline i32x8 ld8_2(const unsigned char* plo, const unsigned char* phi){
  uint4 lo = *(const uint4*)plo, hi = *(const uint4*)phi;
  return (i32x8){(int)lo.x,(int)lo.y,(int)lo.z,(int)lo.w,
                 (int)hi.x,(int)hi.y,(int)hi.z,(int)hi.w};
}

// tbf8: chunk c (16 KB) holds targets t in [c*64,(c+1)*64). Region index
// u = (ki*2+mt)*2+w (1 KB each); inner offset half*512 + m*16 (+q*4 in conv).
// Gemm lane l (m=l&31, half=l>>5) reads region*1024 + lane*16 -> lane-linear
// conflict-free ds_read_b128. abf8: row-major fp8, pre-scaled by s*log2e.

// ---------------- shared device bodies ---------------------------------------
__device__ __forceinline__ void conv_chunk(
    int c, int tid, const float* __restrict__ feat,
    unsigned char* __restrict__ tbf8, float* __restrict__ carr,
    float* __restrict__ diag){
  int r = tid >> 2, q = tid & 3;
  int t = c*64 + r;
  unsigned tb = (unsigned)t / 17u;
  unsigned tk = (unsigned)t - tb*17u;
  const float* trow = feat + ((size_t)tb*RR + tk + 1)*DD;
  const float* arow = feat + (size_t)tb*RR*DD;
  float d = 0.f, qq = 0.f, asq = 0.f;
  unsigned pkv[16];
  #pragma unroll
  for (int i=0;i<16;++i){              // k = 16*i + 4*q + {0..3}
    float4 tv = ((const float4*)trow)[q + 4*i];
    float4 av = ((const float4*)arow)[q + 4*i];
    d   += av.x*tv.x + av.y*tv.y + av.z*tv.z + av.w*tv.w;
    qq  += tv.x*tv.x + tv.y*tv.y + tv.z*tv.z + tv.w*tv.w;
    asq += av.x*av.x + av.y*av.y + av.z*av.z + av.w*av.w;
    pkv[i] = (unsigned)pk8(tv.x, tv.y, tv.z, tv.w);
  }
  int m = r & 31, mt = r >> 5;
  size_t cb = (size_t)c*CHUNK_BYTES;
  #pragma unroll
  for (int i=0;i<16;++i){              // every store = 256-B coalesced run
    int ki = i >> 2, hf = (i >> 1) & 1, w = i & 1;
    *(unsigned*)(tbf8 + cb + (size_t)((ki*2+mt)*2+w)*1024 + hf*512 + m*16 + q*4)
        = pkv[i];
  }
  d   += __shfl_xor(d,1);   d   += __shfl_xor(d,2);
  qq  += __shfl_xor(qq,1);  qq  += __shfl_xor(qq,2);
  asq += __shfl_xor(asq,1); asq += __shfl_xor(asq,2);
  if (q == 0){
    float an = fmaxf(sqrtf(asq), EPSV), tn = fmaxf(sqrtf(qq), EPSV);
    carr[t] = d / (an*tn);
    if (tk == 0) diag[tb] = d;         // raw fp32 anchor.pos
  }
}

__device__ __forceinline__ void conv_anchor(
    int blk, int tid, const float* __restrict__ feat, float s2,
    unsigned char* __restrict__ abf8){
  int a = tid >> 4, j = tid & 15;      // 16 anchors x 16 row-pieces
  int b = blk*16 + a;
  const float* ar = feat + (size_t)b*RR*DD + j*16;
  unsigned o0,o1,o2,o3;
  { float4 v=((const float4*)ar)[0]; o0=(unsigned)pk8(v.x*s2,v.y*s2,v.z*s2,v.w*s2); }
  { float4 v=((const float4*)ar)[1]; o1=(unsigned)pk8(v.x*s2,v.y*s2,v.z*s2,v.w*s2); }
  { float4 v=((const float4*)ar)[2]; o2=(unsigned)pk8(v.x*s2,v.y*s2,v.z*s2,v.w*s2); }
  { float4 v=((const float4*)ar)[3]; o3=(unsigned)pk8(v.x*s2,v.y*s2,v.z*s2,v.w*s2); }
  *(uint4*)(abf8 + (size_t)b*DD + j*16) = make_uint4(o0,o1,o2,o3);
}

__device__ __forceinline__ void gemm_task(
    int mb, int ns, int tid,
    const unsigned char* __restrict__ abf8, const unsigned char* __restrict__ tbf8,
    float* __restrict__ part_m, float* __restrict__ part_s,
    unsigned char (*Bs)[CHUNK_BYTES]){
  const int lane = tid & 63, wave = tid >> 6;
  const int l31 = lane & 31, half = lane >> 5;
  const char* gbase = (const char*)tbf8 + (size_t)(ns*NCHUNK)*CHUNK_BYTES;

  {                                    // stage chunk 0 into Bs[0]
    const char* g = gbase;
    char* l = (char*)Bs[0];
    #pragma unroll
    for (int j=0;j<4;++j) gl_lds16(g + j*4096 + tid*16, l + j*4096 + tid*16);
  }
  i32x8 af[4];                         // anchor frags: n = mb*128+wave*32+l31
  {
    const unsigned char* ab = abf8
        + (size_t)(mb*BMB + wave*BMW + l31)*DD + half*32;
    #pragma unroll
    for (int ki=0;ki<4;++ki)
      af[ki] = ld8_2(ab + ki*64, ab + ki*64 + 16);
  }

  float run_m = -INFINITY, run_s = 0.f;
  for (int ch=0; ch<NCHUNK; ++ch){
    __syncthreads();                   // DMA for ch drained; other buf free
    if (ch+1 < NCHUNK){
      const char* g = gbase + (size_t)(ch+1)*CHUNK_BYTES;
      char* l = (char*)Bs[(ch+1) & 1];
      #pragma unroll
      for (int j=0;j<4;++j) gl_lds16(g + j*4096 + tid*16, l + j*4096 + tid*16);
    }
    const unsigned char* frag = &Bs[ch&1][0] + lane*16;

    f32x16 a0 = (f32x16)(0.f), a1 = (f32x16)(0.f);
    #pragma unroll
    for (int ki=0; ki<4; ++ki){
      i32x8 tf0 = ld8_2(frag + (size_t)((ki*2+0)*2+0)*1024,
                        frag + (size_t)((ki*2+0)*2+1)*1024);
      i32x8 tf1 = ld8_2(frag + (size_t)((ki*2+1)*2+0)*1024,
                        frag + (size_t)((ki*2+1)*2+1)*1024);
      a0 = __builtin_amdgcn_mfma_scale_f32_32x32x64_f8f6f4(tf0, af[ki], a0, 0,0, 0,127, 0,127);
      a1 = __builtin_amdgcn_mfma_scale_f32_32x32x64_f8f6f4(tf1, af[ki], a1, 0,0, 0,127, 0,127);
    }

    // epilogue (log2 domain): in-lane fold over 32 targets
    f32x16 tm = __builtin_elementwise_max(a0, a1);
    float m8[8];
    #pragma unroll
    for (int i=0;i<8;++i) m8[i] = fmaxf(tm[i], tm[i+8]);
    float mx = fmaxf(fmaxf(fmaxf(m8[0],m8[1]),fmaxf(m8[2],m8[3])),
                     fmaxf(fmaxf(m8[4],m8[5]),fmaxf(m8[6],m8[7])));
    f32x16 e;
    #pragma unroll
    for (int i=0;i<16;++i)
      e[i] = __builtin_amdgcn_exp2f(a0[i]-mx) + __builtin_amdgcn_exp2f(a1[i]-mx);
    float s8[8];
    #pragma unroll
    for (int i=0;i<8;++i) s8[i] = e[i] + e[i+8];
    float sh = ((s8[0]+s8[1])+(s8[2]+s8[3]))+((s8[4]+s8[5])+(s8[6]+s8[7]));
    float nm = fmaxf(run_m, mx);
    run_s = run_s*__builtin_amdgcn_exp2f(run_m-nm)
          + sh*__builtin_amdgcn_exp2f(mx-nm);
    run_m = nm;
  }

  int gm = mb*BMB + wave*BMW + l31;
  int slot = ns*2 + half;
  part_m[(size_t)gm*NSLOT + slot] = run_m;
  part_s[(size_t)gm*NSLOT + slot] = run_s;
}

__device__ __forceinline__ void combine_b(
    int b, int lane,
    const float* __restrict__ part_m, const float* __restrict__ part_s,
    const float* __restrict__ diag, const float* __restrict__ carr,
    const float* __restrict__ scores, float s, float* __restrict__ outarr){
  const float* pm = part_m + (size_t)b*NSLOT;
  const float* ps = part_s + (size_t)b*NSLOT;
  float mv[5], sv[5];
  float M = -INFINITY;
  #pragma unroll
  for (int i=0;i<5;++i){
    int idx = lane + i*64;
    bool ok = (idx < NSLOT);
    mv[i] = ok ? pm[idx] : -INFINITY;
    sv[i] = ok ? ps[idx] : 0.f;
    M = fmaxf(M, mv[i]);
  }
  #pragma unroll
  for (int off=1; off<64; off<<=1) M = fmaxf(M, __shfl_xor(M,off));
  float S = 0.f;
  #pragma unroll
  for (int i=0;i<5;++i) S += sv[i]*__builtin_amdgcn_exp2f(mv[i]-M);
  #pragma unroll
  for (int off=1; off<64; off<<=1) S += __shfl_xor(S,off);
  float inf_ = (M + __log2f(S))*LN2 - s*diag[b];   // back to ln domain

  const float* cb = carr + (size_t)b*KT;
  const float* sb = scores + (size_t)b*KT;
  float cv[KT], sw[KT];
  #pragma unroll
  for (int j=0;j<KT;++j){ cv[j] = cb[j]; sw[j] = sb[j]; }
  float cm = -INFINITY, sm = -INFINITY;
  #pragma unroll
  for (int j=0;j<KT;++j){ cm = fmaxf(cm, cv[j]); sm = fmaxf(sm, sw[j]); }
  float cs = 0.f, ss = 0.f;
  #pragma unroll
  for (int j=0;j<KT;++j){
    cs += __builtin_amdgcn_exp2f((cv[j]-cm)*LOG2E);
    ss += __builtin_amdgcn_exp2f((sw[j]-sm)*LOG2E);
  }
  float lse_c = cm + __logf(cs);
  float lse_s = sm + __logf(ss);
  float kl = 0.f;
  #pragma unroll
  for (int j=0;j<KT;++j){
    float lq = sw[j] - lse_s;
    float lp = cv[j] - lse_c;
    kl += __builtin_amdgcn_exp2f(lq*LOG2E)*(lq - lp);
  }
  kl *= (1.0f/KT);
  if (lane == 0) outarr[b] = BETA*kl + ALPHA*inf_;
}

// ---------------- cooperative mega-kernel ------------------------------------
__global__ __launch_bounds__(256,3) void mega_kernel(
    const float* __restrict__ feat, const float* __restrict__ scores,
    const float* __restrict__ lscale,
    int* __restrict__ ctr, float* __restrict__ diag, float* __restrict__ outarr,
    float* __restrict__ carr, float* __restrict__ part_m, float* __restrict__ part_s,
    unsigned char* __restrict__ abf8, unsigned char* __restrict__ tbf8,
    float* __restrict__ out){
  __shared__ __align__(16) unsigned char Bs[2][CHUNK_BYTES];   // 2 x 16 KB
  __shared__ int stask;
  __shared__ float shf[4];
  cg::grid_group grid = cg::this_grid();
  const int tid = threadIdx.x, lane = tid & 63, wave = tid >> 6;
  const int bid = blockIdx.x;

  // Phase 0: convert
  for (int c = bid; c < NCHUNKT; c += GRID)
    conv_chunk(c, tid, feat, tbf8, carr, diag);
  if (bid < 256) conv_anchor(bid, tid, feat, lscale[0]*LOG2E, abf8);
  if (bid == 0 && tid == 0) *ctr = 0;
  grid.sync();

  // Phase 1: gemm + online LSE (dynamic tasks)
  while (true){
    __syncthreads();
    if (tid == 0) stask = atomicAdd(ctr, 1);
    __syncthreads();
    int t = stask;
    if (t >= NTASK) break;
    unsigned mb = (unsigned)t / (unsigned)NSPLIT;
    int ns = t - (int)mb*NSPLIT;
    gemm_task((int)mb, ns, tid, abf8, tbf8, part_m, part_s, Bs);
  }
  grid.sync();

  // Phase 2: combine + KL
  {
    float s = lscale[0];
    for (int b = bid*4 + wave; b < BATCH; b += GRID*4)
      combine_b(b, lane, part_m, part_s, diag, carr, scores, s, outarr);
  }
  grid.sync();

  // Phase 3: final mean (block 0)
  if (bid == 0){
    float v = 0.f;
    for (int i = tid; i < BATCH; i += 256) v += outarr[i];
    #pragma unroll
    for (int off=1; off<64; off<<=1) v += __shfl_xor(v, off);
    if (lane == 0) shf[wave] = v;
    __syncthreads();
    if (tid == 0) out[0] = (shf[0]+shf[1]+shf[2]+shf[3])*(1.0f/BATCH);
  }
}

// ---------------- fallback kernels (same ws layout) --------------------------
__global__ __launch_bounds__(256) void tconv_kernel(
    const float* __restrict__ feat, const float* __restrict__ lscale,
    unsigned char* __restrict__ abf8, unsigned char* __restrict__ tbf8,
    float* __restrict__ carr, float* __restrict__ diag){
  conv_chunk(blockIdx.x, threadIdx.x, feat, tbf8, carr, diag);
  if (blockIdx.x < 256)
    conv_anchor(blockIdx.x, threadIdx.x, feat, lscale[0]*LOG2E, abf8);
}

__global__ __launch_bounds__(256,3) void gemm_kernel(
    const unsigned char* __restrict__ abf8, const unsigned char* __restrict__ tbf8,
    float* __restrict__ part_m, float* __restrict__ part_s){
  __shared__ __align__(16) unsigned char Bs[2][CHUNK_BYTES];
  gemm_task(blockIdx.y, blockIdx.x, threadIdx.x, abf8, tbf8, part_m, part_s, Bs);
}

__global__ __launch_bounds__(256) void combine_kernel(
    const float* __restrict__ part_m, const float* __restrict__ part_s,
    const float* __restrict__ diag, const float* __restrict__ carr,
    const float* __restrict__ scores, const float* __restrict__ lscale,
    float* __restrict__ outarr){
  int b = blockIdx.x*4 + (threadIdx.x >> 6);
  combine_b(b, threadIdx.x & 63, part_m, part_s, diag, carr, scores,
            lscale[0], outarr);
}

__global__ __launch_bounds__(256) void final_kernel(
    const float* __restrict__ outarr, float* __restrict__ out){
  __shared__ float sh[4];
  int tid = threadIdx.x, lane = tid & 63, wv = tid >> 6;
  float v = 0.f;
  for (int i = tid; i < BATCH; i += 256) v += outarr[i];
  #pragma unroll
  for (int off=1; off<64; off<<=1) v += __shfl_xor(v, off);
  if (lane == 0) sh[wv] = v;
  __syncthreads();
  if (tid == 0) out[0] = (sh[0]+sh[1]+sh[2]+sh[3])*(1.0f/BATCH);
}

extern "C" void kernel_launch(void* const* d_in, const int* in_sizes, int n_in,
                              void* d_out, int out_size, void* d_ws, size_t ws_size,
                              hipStream_t stream){
  const float* feat   = (const float*)d_in[0];
  const float* scores = (const float*)d_in[1];
  // d_in[2] row_sizes: shape-only, unused
  const float* lscale = (const float*)d_in[3];

  int*   ctr    = (int*)d_ws;
  float* diag   = (float*)d_ws + 16;                    // 64-B aligned
  float* outarr = diag + BATCH;                         // 4096
  float* carr   = outarr + BATCH;                       // 69632
  float* part_m = carr + NTGT;                          // 4096*272
  float* part_s = part_m + (size_t)BATCH*NSLOT;         // 4096*272
  unsigned char* abf8 = (unsigned char*)(part_s + (size_t)BATCH*NSLOT); // 1 MB
  unsigned char* tbf8 = abf8 + (size_t)BATCH*DD;        // 17.8 MB
  float* outp = (float*)d_out;

  void* args[] = { (void*)&feat, (void*)&scores, (void*)&lscale,
                   (void*)&ctr, (void*)&diag, (void*)&outarr, (void*)&carr,
                   (void*)&part_m, (void*)&part_s, (void*)&abf8, (void*)&tbf8,
                   (void*)&outp };
  hipError_t err = hipLaunchCooperativeKernel((const void*)mega_kernel,
                                              dim3(GRID), dim3(256),
                                              args, 0, stream);
  if (err != hipSuccess){
    (void)hipGetLastError();            // clear error state; use proven path
    tconv_kernel<<<NCHUNKT, 256, 0, stream>>>(feat, lscale, abf8, tbf8, carr, diag);
    gemm_kernel<<<dim3(NSPLIT, MBLK), 256, 0, stream>>>(abf8, tbf8, part_m, part_s);
    combine_kernel<<<BATCH/4, 256, 0, stream>>>(part_m, part_s, diag, carr,
                                                scores, lscale, outarr);
    final_kernel<<<1, 256, 0, stream>>>(outarr, (float*)d_out);
  }
}